// Round 1
// baseline (1384.812 us; speedup 1.0000x reference)
//
#include <hip/hip_runtime.h>
#include <cstdint>

// ---------------------------------------------------------------------------
// HCHA (hypergraph conv with attention), f32.
// N=100000 nodes, M=20000 hyperedges, NNZ=1e6, C=128, HEADS=4, FH=32.
// Structure: counting-sort CSR (by edge and by node) -> gather-based
// aggregations (no float atomics on 128-wide rows).
// ---------------------------------------------------------------------------

__global__ __launch_bounds__(256) void count_deg(const int* __restrict__ node_idx,
                                                 const int* __restrict__ edge_idx,
                                                 unsigned* __restrict__ cnt_n,
                                                 unsigned* __restrict__ cnt_e, int nnz) {
  int i = blockIdx.x * 256 + threadIdx.x;
  if (i < nnz) {
    atomicAdd(&cnt_n[node_idx[i]], 1u);
    atomicAdd(&cnt_e[edge_idx[i]], 1u);
  }
}

__device__ __forceinline__ unsigned wave_incl_scan(unsigned x) {
#pragma unroll
  for (int s = 1; s < 64; s <<= 1) {
    unsigned t = __shfl_up(x, s, 64);
    if ((int)(threadIdx.x & 63) >= s) x += t;
  }
  return x;
}

__global__ __launch_bounds__(1024) void scan_pass1(const unsigned* __restrict__ cnt,
                                                   unsigned* __restrict__ bsum, int L) {
  int i = blockIdx.x * 1024 + threadIdx.x;
  unsigned v = (i < L) ? cnt[i] : 0u;
  unsigned incl = wave_incl_scan(v);
  __shared__ unsigned wsum[16];
  int lane = threadIdx.x & 63, wid = threadIdx.x >> 6;
  if (lane == 63) wsum[wid] = incl;
  __syncthreads();
  if (threadIdx.x == 0) {
    unsigned t = 0;
#pragma unroll
    for (int w = 0; w < 16; ++w) t += wsum[w];
    bsum[blockIdx.x] = t;
  }
}

__global__ __launch_bounds__(1024) void scan_pass2(const unsigned* __restrict__ bsum,
                                                   unsigned* __restrict__ boff, int nb) {
  int i = threadIdx.x;
  unsigned v = (i < nb) ? bsum[i] : 0u;
  unsigned incl = wave_incl_scan(v);
  __shared__ unsigned wsum[16];
  int lane = threadIdx.x & 63, wid = threadIdx.x >> 6;
  if (lane == 63) wsum[wid] = incl;
  __syncthreads();
  unsigned add = 0;
  for (int w = 0; w < wid; ++w) add += wsum[w];
  if (i < nb) boff[i] = add + incl - v;  // exclusive
}

__global__ __launch_bounds__(1024) void scan_pass3(const unsigned* __restrict__ cnt,
                                                   const unsigned* __restrict__ boff,
                                                   unsigned* __restrict__ off,
                                                   unsigned* __restrict__ cur, int L) {
  int i = blockIdx.x * 1024 + threadIdx.x;
  unsigned v = (i < L) ? cnt[i] : 0u;
  unsigned incl = wave_incl_scan(v);
  __shared__ unsigned wsum[16];
  int lane = threadIdx.x & 63, wid = threadIdx.x >> 6;
  if (lane == 63) wsum[wid] = incl;
  __syncthreads();
  unsigned add = boff[blockIdx.x];
  for (int w = 0; w < wid; ++w) add += wsum[w];
  unsigned excl = add + incl - v;
  if (i < L) { off[i] = excl; cur[i] = excl; }
  if (i == L) off[L] = excl;  // total
}

__global__ __launch_bounds__(256) void make_inv(const unsigned* __restrict__ cnt,
                                                float* __restrict__ inv, int L) {
  int i = blockIdx.x * 256 + threadIdx.x;
  if (i < L) inv[i] = cnt[i] ? 1.f / (float)cnt[i] : 0.f;
}

__global__ __launch_bounds__(256) void build_perm(const int* __restrict__ node_idx,
                                                  const int* __restrict__ edge_idx,
                                                  unsigned* __restrict__ ncur,
                                                  unsigned* __restrict__ ecur,
                                                  unsigned* __restrict__ nperm,
                                                  unsigned* __restrict__ eperm, int nnz) {
  int i = blockIdx.x * 256 + threadIdx.x;
  if (i < nnz) {
    unsigned p = atomicAdd(&ecur[edge_idx[i]], 1u);
    eperm[p] = (unsigned)i;
    unsigned q = atomicAdd(&ncur[node_idx[i]], 1u);
    nperm[q] = (unsigned)i;
  }
}

// C[r,o] = sum_k A[r,k] * W[o,k];  A: rows x 128, W: 128 x 128 (row-major)
#define GM 32
__global__ __launch_bounds__(256) void gemm128(const float* __restrict__ A,
                                               const float* __restrict__ W,
                                               float* __restrict__ C, int rows) {
  __shared__ __align__(16) float As[GM][129];   // As[r][k]
  __shared__ __align__(16) float Wt[64][132];   // Wt[k][o], k half-tile
  const int tid = threadIdx.x;
  const int row0 = blockIdx.x * GM;

  for (int idx = tid; idx < GM * 128; idx += 256) {
    int r = idx >> 7, k = idx & 127;
    int gr = row0 + r;
    As[r][k] = (gr < rows) ? A[gr * 128 + k] : 0.f;
  }

  const int tr = tid >> 5, tc = tid & 31;
  const int r0 = tr * 4, c0 = tc * 4;
  float acc[4][4] = {{0.f}};

  for (int kh = 0; kh < 2; ++kh) {
    __syncthreads();  // prev readers done (also covers As staging on kh=0)
    for (int idx = tid; idx < 128 * 64; idx += 256) {
      int o = idx >> 6, k = idx & 63;
      Wt[k][o] = W[o * 128 + kh * 64 + k];
    }
    __syncthreads();
#pragma unroll 4
    for (int k = 0; k < 64; ++k) {
      const int kk = kh * 64 + k;
      float a0 = As[r0 + 0][kk], a1 = As[r0 + 1][kk];
      float a2 = As[r0 + 2][kk], a3 = As[r0 + 3][kk];
      float4 b = *(const float4*)&Wt[k][c0];
      acc[0][0] += a0 * b.x; acc[0][1] += a0 * b.y; acc[0][2] += a0 * b.z; acc[0][3] += a0 * b.w;
      acc[1][0] += a1 * b.x; acc[1][1] += a1 * b.y; acc[1][2] += a1 * b.z; acc[1][3] += a1 * b.w;
      acc[2][0] += a2 * b.x; acc[2][1] += a2 * b.y; acc[2][2] += a2 * b.z; acc[2][3] += a2 * b.w;
      acc[3][0] += a3 * b.x; acc[3][1] += a3 * b.y; acc[3][2] += a3 * b.z; acc[3][3] += a3 * b.w;
    }
  }
#pragma unroll
  for (int i = 0; i < 4; ++i) {
    int gr = row0 + r0 + i;
    if (gr < rows)
      *(float4*)&C[gr * 128 + c0] = make_float4(acc[i][0], acc[i][1], acc[i][2], acc[i][3]);
  }
}

// out[v,h] = sum_f feat[v, h*32+f] * att[h*64 + attoff + f]
__global__ __launch_bounds__(256) void att_dot(const float* __restrict__ feat,
                                               const float* __restrict__ att,
                                               float* __restrict__ outv, int rows, int attoff) {
  int idx = blockIdx.x * 256 + threadIdx.x;
  if (idx >= rows * 4) return;
  int v = idx >> 2, h = idx & 3;
  const float4* fp = (const float4*)(feat + (size_t)v * 128 + h * 32);
  const float4* ap = (const float4*)(att + h * 64 + attoff);
  float s = 0.f;
#pragma unroll
  for (int q = 0; q < 8; ++q) {
    float4 a = ap[q], f = fp[q];
    s += a.x * f.x + a.y * f.y + a.z * f.z + a.w * f.w;
  }
  outv[idx] = s;
}

// per entry: e = exp(leakyrelu(ai+aj)); denom[node,h] += e
__global__ __launch_bounds__(256) void entry_logits(const int* __restrict__ node_idx,
                                                    const int* __restrict__ edge_idx,
                                                    const float* __restrict__ ai,
                                                    const float* __restrict__ aj,
                                                    float* __restrict__ ealpha,
                                                    float* __restrict__ denom, int nnz) {
  int i = blockIdx.x * 256 + threadIdx.x;
  if (i >= nnz) return;
  int n = node_idx[i], e = edge_idx[i];
  float ex[4];
#pragma unroll
  for (int h = 0; h < 4; ++h) {
    float v = ai[n * 4 + h] + aj[e * 4 + h];
    v = v > 0.f ? v : 0.2f * v;
    ex[h] = expf(v);
    atomicAdd(&denom[n * 4 + h], ex[h]);
  }
  *(float4*)&ealpha[(size_t)i * 4] = make_float4(ex[0], ex[1], ex[2], ex[3]);
}

__global__ __launch_bounds__(256) void recip_eps(float* __restrict__ d, int L) {
  int i = blockIdx.x * 256 + threadIdx.x;
  if (i < L) d[i] = 1.f / (d[i] + 1e-16f);
}

// out_e[e,t] = Binv[e] * sum_{entries i of edge e} alpha[i,h] * x1[node_i, t]
__global__ __launch_bounds__(128) void edge_aggregate1(const float* __restrict__ x1,
                                                       const float* __restrict__ ealpha,
                                                       const float* __restrict__ rden,
                                                       const float* __restrict__ binv,
                                                       const int* __restrict__ node_idx,
                                                       const unsigned* __restrict__ eoff,
                                                       const unsigned* __restrict__ eperm,
                                                       float* __restrict__ out_e) {
  int e = blockIdx.x, t = threadIdx.x, h = t >> 5;
  unsigned s = eoff[e], en = eoff[e + 1];
  float acc = 0.f;
  for (unsigned j = s; j < en; ++j) {
    int i = (int)eperm[j];
    int n = node_idx[i];
    float alpha = ealpha[(size_t)i * 4 + h] * rden[n * 4 + h];
    acc += alpha * x1[(size_t)n * 128 + t];
  }
  out_e[(size_t)e * 128 + t] = binv[e] * acc;
}

// h[v,t] = elu(Dinv[v] * rden[v,h] * sum alpha_raw * out_e[edge_i, t] + bias1[t])
__global__ __launch_bounds__(128) void node_aggregate1(const float* __restrict__ out_e,
                                                       const float* __restrict__ ealpha,
                                                       const float* __restrict__ rden,
                                                       const float* __restrict__ dinv,
                                                       const float* __restrict__ bias1,
                                                       const int* __restrict__ edge_idx,
                                                       const unsigned* __restrict__ noff,
                                                       const unsigned* __restrict__ nperm,
                                                       float* __restrict__ hout) {
  int v = blockIdx.x, t = threadIdx.x, h = t >> 5;
  unsigned s = noff[v], en = noff[v + 1];
  float rd = rden[v * 4 + h];
  float acc = 0.f;
  for (unsigned j = s; j < en; ++j) {
    int i = (int)nperm[j];
    int e = edge_idx[i];
    acc += ealpha[(size_t)i * 4 + h] * out_e[(size_t)e * 128 + t];
  }
  float val = dinv[v] * rd * acc + bias1[t];
  hout[(size_t)v * 128 + t] = val > 0.f ? val : expm1f(val);
}

__global__ __launch_bounds__(128) void edge_aggregate2(const float* __restrict__ x2,
                                                       const float* __restrict__ binv,
                                                       const int* __restrict__ node_idx,
                                                       const unsigned* __restrict__ eoff,
                                                       const unsigned* __restrict__ eperm,
                                                       float* __restrict__ oe) {
  int e = blockIdx.x, t = threadIdx.x;
  unsigned s = eoff[e], en = eoff[e + 1];
  float acc = 0.f;
  for (unsigned j = s; j < en; ++j) {
    int i = (int)eperm[j];
    int n = node_idx[i];
    acc += x2[(size_t)n * 128 + t];
  }
  oe[(size_t)e * 128 + t] = binv[e] * acc;
}

__global__ __launch_bounds__(128) void node_aggregate2(const float* __restrict__ oe,
                                                       const float* __restrict__ dinv,
                                                       const float* __restrict__ bias2,
                                                       const int* __restrict__ edge_idx,
                                                       const unsigned* __restrict__ noff,
                                                       const unsigned* __restrict__ nperm,
                                                       float* __restrict__ out) {
  int v = blockIdx.x, t = threadIdx.x;
  unsigned s = noff[v], en = noff[v + 1];
  float acc = 0.f;
  for (unsigned j = s; j < en; ++j) {
    int i = (int)nperm[j];
    int e = edge_idx[i];
    acc += oe[(size_t)e * 128 + t];
  }
  out[(size_t)v * 128 + t] = dinv[v] * acc + bias2[t];
}

extern "C" void kernel_launch(void* const* d_in, const int* in_sizes, int n_in,
                              void* d_out, int out_size, void* d_ws, size_t ws_size,
                              hipStream_t stream) {
  (void)n_in; (void)out_size; (void)ws_size;
  const float* x      = (const float*)d_in[0];
  const float* hea    = (const float*)d_in[1];
  const float* lin1W  = (const float*)d_in[2];
  const float* helinW = (const float*)d_in[3];
  const float* att1   = (const float*)d_in[4];
  const float* bias1  = (const float*)d_in[5];
  const float* lin2W  = (const float*)d_in[6];
  const float* bias2  = (const float*)d_in[7];
  const int* node_idx = (const int*)d_in[8];
  const int* edge_idx = (const int*)d_in[9];
  float* out = (float*)d_out;

  const int N   = in_sizes[0] / 128;
  const int M   = in_sizes[1] / 128;
  const int NNZ = in_sizes[8];

  char* base = (char*)d_ws;
  size_t off = 0;
  auto alloc = [&](size_t bytes) -> char* {
    char* p = base + off;
    off = (off + bytes + 255) & ~(size_t)255;
    return p;
  };
  float* x1    = (float*)alloc((size_t)N * 128 * 4);  // x1, later x2
  float* hbuf  = (float*)alloc((size_t)N * 128 * 4);  // out_n -> h
  float* heoe  = (float*)alloc((size_t)M * 128 * 4);  // he -> out_e -> oe
  float* ai    = (float*)alloc((size_t)N * 4 * 4);
  float* aj    = (float*)alloc((size_t)M * 4 * 4);
  float* dinv  = (float*)alloc((size_t)N * 4);
  float* binv  = (float*)alloc((size_t)M * 4);
  char* zstart = base + off;                           // ---- zeroed region ----
  float* denom    = (float*)alloc((size_t)N * 4 * 4);
  unsigned* cnt_n = (unsigned*)alloc((size_t)N * 4);
  unsigned* cnt_e = (unsigned*)alloc((size_t)M * 4);
  size_t zbytes = (size_t)((base + off) - zstart);     // ---- end zero region ----
  float* ealpha   = (float*)alloc((size_t)NNZ * 4 * 4);
  unsigned* noff  = (unsigned*)alloc((size_t)(N + 1) * 4);
  unsigned* eoff  = (unsigned*)alloc((size_t)(M + 1) * 4);
  unsigned* ncur  = (unsigned*)alloc((size_t)N * 4);
  unsigned* ecur  = (unsigned*)alloc((size_t)M * 4);
  unsigned* nperm = (unsigned*)alloc((size_t)NNZ * 4);
  unsigned* eperm = (unsigned*)alloc((size_t)NNZ * 4);
  unsigned* bsum  = (unsigned*)alloc(1024 * 4);
  unsigned* boff  = (unsigned*)alloc(1024 * 4);

  hipMemsetAsync(zstart, 0, zbytes, stream);

  const int g_nnz = (NNZ + 255) / 256;
  count_deg<<<g_nnz, 256, 0, stream>>>(node_idx, edge_idx, cnt_n, cnt_e, NNZ);

  const int nbE = (M + 1 + 1023) / 1024;
  const int nbN = (N + 1 + 1023) / 1024;
  scan_pass1<<<nbE, 1024, 0, stream>>>(cnt_e, bsum, M);
  scan_pass2<<<1, 1024, 0, stream>>>(bsum, boff, nbE);
  scan_pass3<<<nbE, 1024, 0, stream>>>(cnt_e, boff, eoff, ecur, M);
  scan_pass1<<<nbN, 1024, 0, stream>>>(cnt_n, bsum, N);
  scan_pass2<<<1, 1024, 0, stream>>>(bsum, boff, nbN);
  scan_pass3<<<nbN, 1024, 0, stream>>>(cnt_n, boff, noff, ncur, N);

  make_inv<<<(N + 255) / 256, 256, 0, stream>>>(cnt_n, dinv, N);
  make_inv<<<(M + 255) / 256, 256, 0, stream>>>(cnt_e, binv, M);
  build_perm<<<g_nnz, 256, 0, stream>>>(node_idx, edge_idx, ncur, ecur, nperm, eperm, NNZ);

  gemm128<<<(N + GM - 1) / GM, 256, 0, stream>>>(x, lin1W, x1, N);
  gemm128<<<(M + GM - 1) / GM, 256, 0, stream>>>(hea, helinW, heoe, M);
  att_dot<<<(N * 4 + 255) / 256, 256, 0, stream>>>(x1, att1, ai, N, 0);
  att_dot<<<(M * 4 + 255) / 256, 256, 0, stream>>>(heoe, att1, aj, M, 32);
  entry_logits<<<g_nnz, 256, 0, stream>>>(node_idx, edge_idx, ai, aj, ealpha, denom, NNZ);
  recip_eps<<<(N * 4 + 255) / 256, 256, 0, stream>>>(denom, N * 4);

  edge_aggregate1<<<M, 128, 0, stream>>>(x1, ealpha, denom, binv, node_idx, eoff, eperm, heoe);
  node_aggregate1<<<N, 128, 0, stream>>>(heoe, ealpha, denom, dinv, bias1, edge_idx, noff, nperm, hbuf);

  gemm128<<<(N + GM - 1) / GM, 256, 0, stream>>>(hbuf, lin2W, x1, N);  // x2 aliases x1

  edge_aggregate2<<<M, 128, 0, stream>>>(x1, binv, node_idx, eoff, eperm, heoe);
  node_aggregate2<<<N, 128, 0, stream>>>(heoe, dinv, bias2, edge_idx, noff, nperm, out);
}

// Round 2
// 900.445 us; speedup vs baseline: 1.5379x; 1.5379x over previous
//
#include <hip/hip_runtime.h>
#include <cstdint>

// ---------------------------------------------------------------------------
// HCHA (hypergraph conv with attention), f32.
// N=100000 nodes, M=20000 hyperedges, NNZ=1e6, C=128, HEADS=4, FH=32.
// Counting-sort CSR (by edge and by node) -> gather-based aggregations.
// Softmax denominator via CSR gather (no float atomics).
// Layer-2 GEMM pushed after edge aggregation (M rows, not N).
// ---------------------------------------------------------------------------

__global__ __launch_bounds__(256) void count_deg(const int* __restrict__ node_idx,
                                                 const int* __restrict__ edge_idx,
                                                 unsigned* __restrict__ cnt_n,
                                                 unsigned* __restrict__ cnt_e, int nnz) {
  int i = blockIdx.x * 256 + threadIdx.x;
  if (i < nnz) {
    atomicAdd(&cnt_n[node_idx[i]], 1u);
    atomicAdd(&cnt_e[edge_idx[i]], 1u);
  }
}

__device__ __forceinline__ unsigned wave_incl_scan(unsigned x) {
#pragma unroll
  for (int s = 1; s < 64; s <<= 1) {
    unsigned t = __shfl_up(x, s, 64);
    if ((int)(threadIdx.x & 63) >= s) x += t;
  }
  return x;
}

__global__ __launch_bounds__(1024) void scan_pass1(const unsigned* __restrict__ cnt,
                                                   unsigned* __restrict__ bsum, int L) {
  int i = blockIdx.x * 1024 + threadIdx.x;
  unsigned v = (i < L) ? cnt[i] : 0u;
  unsigned incl = wave_incl_scan(v);
  __shared__ unsigned wsum[16];
  int lane = threadIdx.x & 63, wid = threadIdx.x >> 6;
  if (lane == 63) wsum[wid] = incl;
  __syncthreads();
  if (threadIdx.x == 0) {
    unsigned t = 0;
#pragma unroll
    for (int w = 0; w < 16; ++w) t += wsum[w];
    bsum[blockIdx.x] = t;
  }
}

__global__ __launch_bounds__(1024) void scan_pass2(const unsigned* __restrict__ bsum,
                                                   unsigned* __restrict__ boff, int nb) {
  int i = threadIdx.x;
  unsigned v = (i < nb) ? bsum[i] : 0u;
  unsigned incl = wave_incl_scan(v);
  __shared__ unsigned wsum[16];
  int lane = threadIdx.x & 63, wid = threadIdx.x >> 6;
  if (lane == 63) wsum[wid] = incl;
  __syncthreads();
  unsigned add = 0;
  for (int w = 0; w < wid; ++w) add += wsum[w];
  if (i < nb) boff[i] = add + incl - v;  // exclusive
}

__global__ __launch_bounds__(1024) void scan_pass3(const unsigned* __restrict__ cnt,
                                                   const unsigned* __restrict__ boff,
                                                   unsigned* __restrict__ off,
                                                   unsigned* __restrict__ cur, int L) {
  int i = blockIdx.x * 1024 + threadIdx.x;
  unsigned v = (i < L) ? cnt[i] : 0u;
  unsigned incl = wave_incl_scan(v);
  __shared__ unsigned wsum[16];
  int lane = threadIdx.x & 63, wid = threadIdx.x >> 6;
  if (lane == 63) wsum[wid] = incl;
  __syncthreads();
  unsigned add = boff[blockIdx.x];
  for (int w = 0; w < wid; ++w) add += wsum[w];
  unsigned excl = add + incl - v;
  if (i < L) { off[i] = excl; cur[i] = excl; }
  if (i == L) off[L] = excl;  // total
}

__global__ __launch_bounds__(256) void make_inv(const unsigned* __restrict__ cnt,
                                                float* __restrict__ inv, int L) {
  int i = blockIdx.x * 256 + threadIdx.x;
  if (i < L) inv[i] = cnt[i] ? 1.f / (float)cnt[i] : 0.f;
}

__global__ __launch_bounds__(256) void build_perm(const int* __restrict__ node_idx,
                                                  const int* __restrict__ edge_idx,
                                                  unsigned* __restrict__ ncur,
                                                  unsigned* __restrict__ ecur,
                                                  unsigned* __restrict__ nperm,
                                                  unsigned* __restrict__ eperm, int nnz) {
  int i = blockIdx.x * 256 + threadIdx.x;
  if (i < nnz) {
    unsigned p = atomicAdd(&ecur[edge_idx[i]], 1u);
    eperm[p] = (unsigned)i;
    unsigned q = atomicAdd(&ncur[node_idx[i]], 1u);
    nperm[q] = (unsigned)i;
  }
}

// C[r,o] = sum_k A[r,k] * W[o,k];  A: rows x 128, W: 128 x 128 (row-major)
#define GM 32
__global__ __launch_bounds__(256) void gemm128(const float* __restrict__ A,
                                               const float* __restrict__ W,
                                               float* __restrict__ C, int rows) {
  __shared__ __align__(16) float Ast[128 * 36];  // Ast[k][r], r-pad to 36
  __shared__ __align__(16) float Wt[64 * 132];   // Wt[k][o], k half-tile
  const int tid = threadIdx.x;
  const int row0 = blockIdx.x * GM;

  for (int idx = tid; idx < GM * 128; idx += 256) {
    int r = idx >> 7, k = idx & 127;
    int gr = row0 + r;
    Ast[k * 36 + r] = (gr < rows) ? A[(size_t)gr * 128 + k] : 0.f;
  }

  const int tr = tid >> 5, tc = tid & 31;
  const int r0 = tr * 4, c0 = tc * 4;
  float acc[4][4] = {{0.f}};

  for (int kh = 0; kh < 2; ++kh) {
    __syncthreads();  // Ast ready / prev-compute done
    for (int idx = tid; idx < 128 * 64; idx += 256) {
      int o = idx >> 6, k = idx & 63;
      Wt[k * 132 + o] = W[o * 128 + kh * 64 + k];
    }
    __syncthreads();
#pragma unroll 8
    for (int k = 0; k < 64; ++k) {
      const int kk = kh * 64 + k;
      float4 a = *(const float4*)&Ast[kk * 36 + r0];
      float4 b = *(const float4*)&Wt[k * 132 + c0];
      acc[0][0] += a.x * b.x; acc[0][1] += a.x * b.y; acc[0][2] += a.x * b.z; acc[0][3] += a.x * b.w;
      acc[1][0] += a.y * b.x; acc[1][1] += a.y * b.y; acc[1][2] += a.y * b.z; acc[1][3] += a.y * b.w;
      acc[2][0] += a.z * b.x; acc[2][1] += a.z * b.y; acc[2][2] += a.z * b.z; acc[2][3] += a.z * b.w;
      acc[3][0] += a.w * b.x; acc[3][1] += a.w * b.y; acc[3][2] += a.w * b.z; acc[3][3] += a.w * b.w;
    }
  }
#pragma unroll
  for (int i = 0; i < 4; ++i) {
    int gr = row0 + r0 + i;
    if (gr < rows)
      *(float4*)&C[(size_t)gr * 128 + c0] = make_float4(acc[i][0], acc[i][1], acc[i][2], acc[i][3]);
  }
}

// ai[v,h] = sum_f feat[v, h*32+f] * att[h*64 + f]   (left half of att1)
__global__ __launch_bounds__(256) void att_dot(const float* __restrict__ feat,
                                               const float* __restrict__ att,
                                               float* __restrict__ outv, int rows) {
  int idx = blockIdx.x * 256 + threadIdx.x;
  if (idx >= rows * 4) return;
  int v = idx >> 2, h = idx & 3;
  const float4* fp = (const float4*)(feat + (size_t)v * 128 + h * 32);
  const float4* ap = (const float4*)(att + h * 64);
  float s = 0.f;
#pragma unroll
  for (int q = 0; q < 8; ++q) {
    float4 a = ap[q], f = fp[q];
    s += a.x * f.x + a.y * f.y + a.z * f.z + a.w * f.w;
  }
  outv[idx] = s;
}

// u[h,k] = sum_f att1[h*64+32+f] * W_he[(h*32+f)*128 + k]   (4 x 128)
__global__ __launch_bounds__(256) void make_u(const float* __restrict__ W_he,
                                              const float* __restrict__ att1,
                                              float* __restrict__ u) {
  int idx = blockIdx.x * 256 + threadIdx.x;
  if (idx >= 512) return;
  int h = idx >> 7, k = idx & 127;
  float s = 0.f;
#pragma unroll
  for (int f = 0; f < 32; ++f)
    s += att1[h * 64 + 32 + f] * W_he[(size_t)(h * 32 + f) * 128 + k];
  u[h * 128 + k] = s;
}

// aj[e,h] = hea[e,:] . u[h,:]
__global__ __launch_bounds__(256) void att_dot_full(const float* __restrict__ feat,
                                                    const float* __restrict__ u,
                                                    float* __restrict__ outv, int rows) {
  int idx = blockIdx.x * 256 + threadIdx.x;
  if (idx >= rows * 4) return;
  int v = idx >> 2, h = idx & 3;
  const float4* fp = (const float4*)(feat + (size_t)v * 128);
  const float4* up = (const float4*)(u + h * 128);
  float s = 0.f;
#pragma unroll
  for (int q = 0; q < 32; ++q) {
    float4 a = up[q], f = fp[q];
    s += a.x * f.x + a.y * f.y + a.z * f.z + a.w * f.w;
  }
  outv[idx] = s;
}

// ealpha[i,h] = exp(leakyrelu(ai[n,h] + aj[e,h]))   (no atomics)
__global__ __launch_bounds__(256) void entry_exp(const int* __restrict__ node_idx,
                                                 const int* __restrict__ edge_idx,
                                                 const float* __restrict__ ai,
                                                 const float* __restrict__ aj,
                                                 float* __restrict__ ealpha, int nnz) {
  int i = blockIdx.x * 256 + threadIdx.x;
  if (i >= nnz) return;
  int n = node_idx[i], e = edge_idx[i];
  float4 av = *(const float4*)&ai[(size_t)n * 4];
  float4 bv = *(const float4*)&aj[(size_t)e * 4];
  float v0 = av.x + bv.x, v1 = av.y + bv.y, v2 = av.z + bv.z, v3 = av.w + bv.w;
  v0 = v0 > 0.f ? v0 : 0.2f * v0;
  v1 = v1 > 0.f ? v1 : 0.2f * v1;
  v2 = v2 > 0.f ? v2 : 0.2f * v2;
  v3 = v3 > 0.f ? v3 : 0.2f * v3;
  *(float4*)&ealpha[(size_t)i * 4] = make_float4(expf(v0), expf(v1), expf(v2), expf(v3));
}

// rden[v,h] = 1 / (sum_{entries of v} ealpha + 1e-16)  via node CSR gather
__global__ __launch_bounds__(256) void node_denom(const unsigned* __restrict__ noff,
                                                  const unsigned* __restrict__ nperm,
                                                  const float* __restrict__ ealpha,
                                                  float* __restrict__ rden, int N) {
  int v = blockIdx.x * 256 + threadIdx.x;
  if (v >= N) return;
  unsigned s = noff[v], en = noff[v + 1];
  float x = 0.f, y = 0.f, z = 0.f, w = 0.f;
  unsigned j = s;
  for (; j + 2 <= en; j += 2) {
    float4 a = *(const float4*)&ealpha[(size_t)nperm[j] * 4];
    float4 b = *(const float4*)&ealpha[(size_t)nperm[j + 1] * 4];
    x += a.x + b.x; y += a.y + b.y; z += a.z + b.z; w += a.w + b.w;
  }
  if (j < en) {
    float4 a = *(const float4*)&ealpha[(size_t)nperm[j] * 4];
    x += a.x; y += a.y; z += a.z; w += a.w;
  }
  *(float4*)&rden[(size_t)v * 4] = make_float4(1.f / (x + 1e-16f), 1.f / (y + 1e-16f),
                                               1.f / (z + 1e-16f), 1.f / (w + 1e-16f));
}

#define ECH 256
// out_e[e,t] = Binv[e] * sum_i alpha_norm[i,h] * x1[node_i, t]
__global__ __launch_bounds__(128) void edge_aggregate1(const float* __restrict__ x1,
                                                       const float* __restrict__ ealpha,
                                                       const float* __restrict__ rden,
                                                       const float* __restrict__ binv,
                                                       const int* __restrict__ node_idx,
                                                       const unsigned* __restrict__ eoff,
                                                       const unsigned* __restrict__ eperm,
                                                       float* __restrict__ out_e) {
  __shared__ int nid[ECH];
  __shared__ float wal[ECH][4];
  int e = blockIdx.x, t = threadIdx.x, h = t >> 5;
  unsigned s = eoff[e], en = eoff[e + 1];
  float a0 = 0.f, a1 = 0.f, a2 = 0.f, a3 = 0.f;
  for (unsigned base = s; base < en; base += ECH) {
    int cnt = (int)min((unsigned)ECH, en - base);
    __syncthreads();
    for (int c = t; c < cnt; c += 128) {
      int i = (int)eperm[base + c];
      int n = node_idx[i];
      nid[c] = n;
      float4 ea = *(const float4*)&ealpha[(size_t)i * 4];
      float4 rd = *(const float4*)&rden[(size_t)n * 4];
      wal[c][0] = ea.x * rd.x; wal[c][1] = ea.y * rd.y;
      wal[c][2] = ea.z * rd.z; wal[c][3] = ea.w * rd.w;
    }
    __syncthreads();
    int c = 0;
    for (; c + 4 <= cnt; c += 4) {
      int n0 = nid[c], n1 = nid[c + 1], n2 = nid[c + 2], n3 = nid[c + 3];
      float w0 = wal[c][h], w1 = wal[c + 1][h], w2 = wal[c + 2][h], w3 = wal[c + 3][h];
      a0 += w0 * x1[(size_t)n0 * 128 + t];
      a1 += w1 * x1[(size_t)n1 * 128 + t];
      a2 += w2 * x1[(size_t)n2 * 128 + t];
      a3 += w3 * x1[(size_t)n3 * 128 + t];
    }
    for (; c < cnt; ++c) a0 += wal[c][h] * x1[(size_t)nid[c] * 128 + t];
  }
  out_e[(size_t)e * 128 + t] = binv[e] * (a0 + a1 + a2 + a3);
}

// h[v,t] = elu(Dinv[v]*rden[v,h] * sum_i ealpha[i,h]*out_e[edge_i,t] + bias1[t])
__global__ __launch_bounds__(128) void node_aggregate1(const float* __restrict__ out_e,
                                                       const float* __restrict__ ealpha,
                                                       const float* __restrict__ rden,
                                                       const float* __restrict__ dinv,
                                                       const float* __restrict__ bias1,
                                                       const int* __restrict__ edge_idx,
                                                       const unsigned* __restrict__ noff,
                                                       const unsigned* __restrict__ nperm,
                                                       float* __restrict__ hout) {
  int v = blockIdx.x, t = threadIdx.x, h = t >> 5;
  unsigned s = noff[v], en = noff[v + 1];
  float rd = dinv[v] * rden[v * 4 + h];
  float a0 = 0.f, a1 = 0.f, a2 = 0.f, a3 = 0.f;
  unsigned j = s;
  for (; j + 4 <= en; j += 4) {
    int i0 = (int)nperm[j], i1 = (int)nperm[j + 1], i2 = (int)nperm[j + 2], i3 = (int)nperm[j + 3];
    int e0 = edge_idx[i0], e1 = edge_idx[i1], e2 = edge_idx[i2], e3 = edge_idx[i3];
    a0 += ealpha[(size_t)i0 * 4 + h] * out_e[(size_t)e0 * 128 + t];
    a1 += ealpha[(size_t)i1 * 4 + h] * out_e[(size_t)e1 * 128 + t];
    a2 += ealpha[(size_t)i2 * 4 + h] * out_e[(size_t)e2 * 128 + t];
    a3 += ealpha[(size_t)i3 * 4 + h] * out_e[(size_t)e3 * 128 + t];
  }
  for (; j < en; ++j) {
    int i0 = (int)nperm[j];
    a0 += ealpha[(size_t)i0 * 4 + h] * out_e[(size_t)edge_idx[i0] * 128 + t];
  }
  float val = rd * (a0 + a1 + a2 + a3) + bias1[t];
  hout[(size_t)v * 128 + t] = val > 0.f ? val : expm1f(val);
}

// oe_pre[e,t] = Binv[e] * sum_i h[node_i, t]
__global__ __launch_bounds__(128) void edge_aggregate2(const float* __restrict__ hfeat,
                                                       const float* __restrict__ binv,
                                                       const int* __restrict__ node_idx,
                                                       const unsigned* __restrict__ eoff,
                                                       const unsigned* __restrict__ eperm,
                                                       float* __restrict__ oe) {
  __shared__ int nid[ECH];
  int e = blockIdx.x, t = threadIdx.x;
  unsigned s = eoff[e], en = eoff[e + 1];
  float a0 = 0.f, a1 = 0.f, a2 = 0.f, a3 = 0.f;
  for (unsigned base = s; base < en; base += ECH) {
    int cnt = (int)min((unsigned)ECH, en - base);
    __syncthreads();
    for (int c = t; c < cnt; c += 128) nid[c] = node_idx[eperm[base + c]];
    __syncthreads();
    int c = 0;
    for (; c + 4 <= cnt; c += 4) {
      int n0 = nid[c], n1 = nid[c + 1], n2 = nid[c + 2], n3 = nid[c + 3];
      a0 += hfeat[(size_t)n0 * 128 + t];
      a1 += hfeat[(size_t)n1 * 128 + t];
      a2 += hfeat[(size_t)n2 * 128 + t];
      a3 += hfeat[(size_t)n3 * 128 + t];
    }
    for (; c < cnt; ++c) a0 += hfeat[(size_t)nid[c] * 128 + t];
  }
  oe[(size_t)e * 128 + t] = binv[e] * (a0 + a1 + a2 + a3);
}

// out[v,t] = Dinv[v] * sum_i oe2[edge_i, t] + bias2[t]
__global__ __launch_bounds__(128) void node_aggregate2(const float* __restrict__ oe2,
                                                       const float* __restrict__ dinv,
                                                       const float* __restrict__ bias2,
                                                       const int* __restrict__ edge_idx,
                                                       const unsigned* __restrict__ noff,
                                                       const unsigned* __restrict__ nperm,
                                                       float* __restrict__ out) {
  int v = blockIdx.x, t = threadIdx.x;
  unsigned s = noff[v], en = noff[v + 1];
  float a0 = 0.f, a1 = 0.f, a2 = 0.f, a3 = 0.f;
  unsigned j = s;
  for (; j + 4 <= en; j += 4) {
    int e0 = edge_idx[nperm[j]], e1 = edge_idx[nperm[j + 1]];
    int e2 = edge_idx[nperm[j + 2]], e3 = edge_idx[nperm[j + 3]];
    a0 += oe2[(size_t)e0 * 128 + t];
    a1 += oe2[(size_t)e1 * 128 + t];
    a2 += oe2[(size_t)e2 * 128 + t];
    a3 += oe2[(size_t)e3 * 128 + t];
  }
  for (; j < en; ++j) a0 += oe2[(size_t)edge_idx[nperm[j]] * 128 + t];
  out[(size_t)v * 128 + t] = dinv[v] * (a0 + a1 + a2 + a3) + bias2[t];
}

extern "C" void kernel_launch(void* const* d_in, const int* in_sizes, int n_in,
                              void* d_out, int out_size, void* d_ws, size_t ws_size,
                              hipStream_t stream) {
  (void)n_in; (void)out_size; (void)ws_size;
  const float* x      = (const float*)d_in[0];
  const float* hea    = (const float*)d_in[1];
  const float* lin1W  = (const float*)d_in[2];
  const float* helinW = (const float*)d_in[3];
  const float* att1   = (const float*)d_in[4];
  const float* bias1  = (const float*)d_in[5];
  const float* lin2W  = (const float*)d_in[6];
  const float* bias2  = (const float*)d_in[7];
  const int* node_idx = (const int*)d_in[8];
  const int* edge_idx = (const int*)d_in[9];
  float* out = (float*)d_out;

  const int N   = in_sizes[0] / 128;
  const int M   = in_sizes[1] / 128;
  const int NNZ = in_sizes[8];

  char* base = (char*)d_ws;
  size_t off = 0;
  auto alloc = [&](size_t bytes) -> char* {
    char* p = base + off;
    off = (off + bytes + 255) & ~(size_t)255;
    return p;
  };
  float* x1    = (float*)alloc((size_t)N * 128 * 4);  // x1; later oe2 (M rows)
  float* hbuf  = (float*)alloc((size_t)N * 128 * 4);  // h
  float* heoe  = (float*)alloc((size_t)M * 128 * 4);  // out_e -> oe_pre
  float* ai    = (float*)alloc((size_t)N * 4 * 4);
  float* aj    = (float*)alloc((size_t)M * 4 * 4);
  float* u     = (float*)alloc(512 * 4);
  float* dinv  = (float*)alloc((size_t)N * 4);
  float* binv  = (float*)alloc((size_t)M * 4);
  float* rden  = (float*)alloc((size_t)N * 4 * 4);
  char* zstart = base + off;                           // ---- zeroed region ----
  unsigned* cnt_n = (unsigned*)alloc((size_t)N * 4);
  unsigned* cnt_e = (unsigned*)alloc((size_t)M * 4);
  size_t zbytes = (size_t)((base + off) - zstart);     // ---- end zero region ----
  float* ealpha   = (float*)alloc((size_t)NNZ * 4 * 4);
  unsigned* noff  = (unsigned*)alloc((size_t)(N + 1) * 4);
  unsigned* eoff  = (unsigned*)alloc((size_t)(M + 1) * 4);
  unsigned* ncur  = (unsigned*)alloc((size_t)N * 4);
  unsigned* ecur  = (unsigned*)alloc((size_t)M * 4);
  unsigned* nperm = (unsigned*)alloc((size_t)NNZ * 4);
  unsigned* eperm = (unsigned*)alloc((size_t)NNZ * 4);
  unsigned* bsum  = (unsigned*)alloc(1024 * 4);
  unsigned* boff  = (unsigned*)alloc(1024 * 4);

  hipMemsetAsync(zstart, 0, zbytes, stream);

  const int g_nnz = (NNZ + 255) / 256;
  count_deg<<<g_nnz, 256, 0, stream>>>(node_idx, edge_idx, cnt_n, cnt_e, NNZ);

  const int nbE = (M + 1 + 1023) / 1024;
  const int nbN = (N + 1 + 1023) / 1024;
  scan_pass1<<<nbE, 1024, 0, stream>>>(cnt_e, bsum, M);
  scan_pass2<<<1, 1024, 0, stream>>>(bsum, boff, nbE);
  scan_pass3<<<nbE, 1024, 0, stream>>>(cnt_e, boff, eoff, ecur, M);
  scan_pass1<<<nbN, 1024, 0, stream>>>(cnt_n, bsum, N);
  scan_pass2<<<1, 1024, 0, stream>>>(bsum, boff, nbN);
  scan_pass3<<<nbN, 1024, 0, stream>>>(cnt_n, boff, noff, ncur, N);

  make_inv<<<(N + 255) / 256, 256, 0, stream>>>(cnt_n, dinv, N);
  make_inv<<<(M + 255) / 256, 256, 0, stream>>>(cnt_e, binv, M);
  build_perm<<<g_nnz, 256, 0, stream>>>(node_idx, edge_idx, ncur, ecur, nperm, eperm, NNZ);

  make_u<<<2, 256, 0, stream>>>(helinW, att1, u);
  gemm128<<<(N + GM - 1) / GM, 256, 0, stream>>>(x, lin1W, x1, N);
  att_dot<<<(N * 4 + 255) / 256, 256, 0, stream>>>(x1, att1, ai, N);
  att_dot_full<<<(M * 4 + 255) / 256, 256, 0, stream>>>(hea, u, aj, M);
  entry_exp<<<g_nnz, 256, 0, stream>>>(node_idx, edge_idx, ai, aj, ealpha, NNZ);
  node_denom<<<(N + 255) / 256, 256, 0, stream>>>(noff, nperm, ealpha, rden, N);

  edge_aggregate1<<<M, 128, 0, stream>>>(x1, ealpha, rden, binv, node_idx, eoff, eperm, heoe);
  node_aggregate1<<<N, 128, 0, stream>>>(heoe, ealpha, rden, dinv, bias1, edge_idx, noff, nperm, hbuf);

  edge_aggregate2<<<M, 128, 0, stream>>>(hbuf, binv, node_idx, eoff, eperm, heoe);
  gemm128<<<(M + GM - 1) / GM, 256, 0, stream>>>(heoe, lin2W, x1, M);  // oe2 into x1 buf
  node_aggregate2<<<N, 128, 0, stream>>>(x1, dinv, bias2, edge_idx, noff, nperm, out);
}